// Round 1
// 805.553 us; speedup vs baseline: 1.0231x; 1.0231x over previous
//
#include <hip/hip_runtime.h>

typedef __attribute__((ext_vector_type(8))) short short8;
typedef __attribute__((ext_vector_type(4))) float f32x4;

#define AS1 __attribute__((address_space(1)))
#define AS3 __attribute__((address_space(3)))

// sizes
#define NB 16384      // batch
#define LDIM 256
#define CDIM 512
#define HDIM 1024

__device__ __forceinline__ unsigned short f2bf(float x) {
    unsigned u = __float_as_uint(x);
    u += 0x7fffu + ((u >> 16) & 1u);   // RNE; inputs are finite, no NaN guard needed
    return (unsigned short)(u >> 16);
}

__device__ __forceinline__ void gld_lds16(const unsigned short* g, unsigned short* l) {
    __builtin_amdgcn_global_load_lds((const AS1 void*)g, (AS3 void*)l, 16, 0, 0);
}

__device__ __forceinline__ float tanh_fast(float x) {
    x = fminf(fmaxf(x, -15.f), 15.f);
    float e = __expf(2.f * x);
    return (e - 1.f) / (e + 1.f);
}

// ---------------- weight conversion / transpose ----------------
// W1T (2048 x 1024 bf16): rows 0..1023 = Wc1^T, rows 1024..2047 = Wh1^T (k<512), 0 else
// W2T (512 x 1024 bf16):  rows 0..255  = Wc2^T, rows 256..511  = Wh2^T
// bias1 (2048 f32) = [bc1|bh1]; bias2 (512 f32) = [bc2|bh2]
__global__ void build_w(const float* __restrict__ Wc1, const float* __restrict__ bc1,
                        const float* __restrict__ Wc2, const float* __restrict__ bc2,
                        const float* __restrict__ Wh1, const float* __restrict__ bh1,
                        const float* __restrict__ Wh2, const float* __restrict__ bh2,
                        unsigned short* __restrict__ W1T, unsigned short* __restrict__ W2T,
                        float* __restrict__ bias1, float* __restrict__ bias2)
{
    const int R1 = 2048 * 1024;
    const int R2 = R1 + 512 * 1024;
    const int R3 = R2 + 2048;
    const int R4 = R3 + 512;
    int id = blockIdx.x * 256 + threadIdx.x;
    if (id < R1) {
        int n = id >> 10, k = id & 1023;
        float v;
        if (n < 1024) v = Wc1[k * 1024 + n];
        else          v = (k < 512) ? Wh1[k * 1024 + (n - 1024)] : 0.f;
        W1T[id] = f2bf(v);
    } else if (id < R2) {
        int id2 = id - R1;
        int n = id2 >> 10, k = id2 & 1023;
        float v = (n < 256) ? Wc2[k * 256 + n] : Wh2[k * 256 + (n - 256)];
        W2T[id2] = f2bf(v);
    } else if (id < R3) {
        int n = id - R2;
        bias1[n] = (n < 1024) ? bc1[n] : bh1[n - 1024];
    } else if (id < R4) {
        int n = id - R3;
        bias2[n] = (n < 256) ? bc2[n] : bh2[n - 256];
    }
}

// ---------------- A1 = bf16([pm | ctx[:, i]])  (16384 x 1024), 8 elems/thread --------
// Also pre-zeroes out's dkl slots (drift[512], dif[512]) for the fused gemm2's atomics.
__global__ void build_A1(const float* __restrict__ z, const float* __restrict__ ts,
                         const float* __restrict__ t, const float* __restrict__ ctx,
                         unsigned short* __restrict__ A1, float* __restrict__ out)
{
    __shared__ int sh_i;
    if (threadIdx.x == 0) {
        float tv = t[0];
        int c = 0;
        #pragma unroll
        for (int q = 0; q < 16; ++q) c += (ts[q] <= tv) ? 1 : 0;   // searchsorted 'right'
        sh_i = (c < 15) ? c : 15;
    }
    __syncthreads();
    const int i = sh_i;
    size_t id = (size_t)blockIdx.x * 256 + threadIdx.x;   // 2,097,152 threads (grid 8192)
    int b  = (int)(id >> 7);
    int c0 = ((int)id & 127) << 3;
    short8 v;
    if (c0 < 512) {
        const float* zp = z + (size_t)b * 513 + c0;        // row base not 16B-aligned (513)
        #pragma unroll
        for (int q = 0; q < 8; ++q) v[q] = (short)f2bf(zp[q]);
    } else {
        const f32x4* cp = (const f32x4*)(ctx + ((size_t)b * 16 + i) * 512 + (c0 - 512));
        f32x4 x0 = cp[0], x1 = cp[1];
        #pragma unroll
        for (int q = 0; q < 4; ++q) { v[q] = (short)f2bf(x0[q]); v[4 + q] = (short)f2bf(x1[q]); }
    }
    *(short8*)(A1 + id * 8) = v;
    if (id < NB) {
        out[id * 513 + 512] = 0.f;                          // drift dkl slot (atomic target)
        out[(size_t)NB * 513 + id * 513 + 512] = 0.f;       // diffusion dkl slot
    }
}

// ---------------- layer-1 bf16 MFMA GEMM, m97 structure, XCD-swizzled ----------------
// 128x128 tile, BK=32, 4 waves of 64x64, 16x16x32 MFMA.
// C = tanh(A1 @ W1 + bias1) -> H bf16 (ldc 2048); ntile>=8 (prior half) uses K=512
__global__ __launch_bounds__(256)
void gemm1(const unsigned short* __restrict__ A, const unsigned short* __restrict__ BT,
           const float* __restrict__ bias, unsigned short* __restrict__ Hout)
{
    __shared__ unsigned short sA[128 * 32];
    __shared__ unsigned short sB[128 * 32];

    const int tid  = threadIdx.x;
    const int lane = tid & 63;
    const int wave = tid >> 6;

    // XCD swizzle: 2048 wgs, 8 XCDs -> 256-wg contiguous chunk per XCD.
    // Each XCD then sees 16 consecutive m-tiles (A1 panel reuse stays in its L2).
    int lin = blockIdx.y * 16 + blockIdx.x;
    lin = (lin & 7) * 256 + (lin >> 3);         // bijective (2048 % 8 == 0)
    const int ntile = lin & 15;
    const int mtile = lin >> 4;
    const int kdim  = (ntile < 8) ? 1024 : 512;

    const int m0 = mtile * 128;
    const int n0 = ntile * 128;

    const int row0 = tid >> 2,         cb0 = tid & 3;
    const int row1 = (256 + tid) >> 2, cb1 = (256 + tid) & 3;

    const unsigned short* aG0 = A + (size_t)(m0 + row0) * 1024 + cb0 * 8;
    const unsigned short* aG1 = A + (size_t)(m0 + row1) * 1024 + cb1 * 8;
    const unsigned short* bG0 = BT + (size_t)(n0 + row0) * 1024 + cb0 * 8;
    const unsigned short* bG1 = BT + (size_t)(n0 + row1) * 1024 + cb1 * 8;

    // wave-uniform LDS bases (HW adds lane*16B)
    unsigned short* sA0 = sA + (size_t)(wave * 64) * 8;
    unsigned short* sA1 = sA + (size_t)(256 + wave * 64) * 8;
    unsigned short* sB0 = sB + (size_t)(wave * 64) * 8;
    unsigned short* sB1 = sB + (size_t)(256 + wave * 64) * 8;

    const int wm = (wave & 1) * 64;
    const int wn = (wave >> 1) * 64;
    const int lr = lane & 15;
    const int kq = (lane >> 4) * 8;

    f32x4 acc[4][4] = {};

    for (int k0 = 0; k0 < kdim; k0 += 32) {
        gld_lds16(aG0 + k0, sA0);
        gld_lds16(aG1 + k0, sA1);
        gld_lds16(bG0 + k0, sB0);
        gld_lds16(bG1 + k0, sB1);
        __syncthreads();

        short8 af[4], bfr[4];
        #pragma unroll
        for (int i = 0; i < 4; ++i)
            af[i] = *(const short8*)&sA[(wm + i * 16 + lr) * 32 + kq];
        #pragma unroll
        for (int i = 0; i < 4; ++i)
            bfr[i] = *(const short8*)&sB[(wn + i * 16 + lr) * 32 + kq];

        #pragma unroll
        for (int i = 0; i < 4; ++i)
            #pragma unroll
            for (int j = 0; j < 4; ++j)
                acc[i][j] = __builtin_amdgcn_mfma_f32_16x16x32_bf16(af[i], bfr[j], acc[i][j], 0, 0, 0);
        __syncthreads();
    }

    // epilogue: C/D layout col=lane&15, row=(lane>>4)*4+reg
    const int rquad = (lane >> 4) * 4;
    #pragma unroll
    for (int i = 0; i < 4; ++i) {
        const int gr = m0 + wm + i * 16 + rquad;
        #pragma unroll
        for (int j = 0; j < 4; ++j) {
            const int gc = n0 + wn + j * 16 + lr;
            const float bs = bias[gc];
            #pragma unroll
            for (int r = 0; r < 4; ++r) {
                float x = acc[i][j][r] + bs;
                Hout[(size_t)(gr + r) * 2048 + gc] = f2bf(tanh_fast(x));
            }
        }
    }
}

// ---------------- layer-2 GEMM fused with final assembly + dkl ----------------
// Each block: 64 rows x 128 cols of BOTH posterior (H[:,0:1024] @ Wc2) and prior
// (H[:,1024:2048] @ Wh2). difference is block-local -> per-row dkl partial via
// 16-lane shuffle tree + atomicAdd (8 adds/row total). Writes drift/diffusion directly.
__global__ __launch_bounds__(256)
void gemm2_fused(const unsigned short* __restrict__ Hm, const unsigned short* __restrict__ W2T,
                 const float* __restrict__ bias2, const float* __restrict__ z,
                 const float* __restrict__ im, const float* __restrict__ dfu,
                 float* __restrict__ out)
{
    __shared__ unsigned short sAp[64 * 32];    // posterior A tile (H cols k0..k0+31)
    __shared__ unsigned short sAq[64 * 32];    // prior    A tile (H cols 1024+k0..)
    __shared__ unsigned short sBp[128 * 32];   // Wc2^T rows n0..n0+127
    __shared__ unsigned short sBq[128 * 32];   // Wh2^T rows 256+n0..

    const int tid  = threadIdx.x;
    const int lane = tid & 63;
    const int wave = tid >> 6;

    // XCD swizzle: 512 wgs -> 64 contiguous per XCD (H panel locality)
    int lin = blockIdx.y * 2 + blockIdx.x;
    lin = (lin & 7) * 64 + (lin >> 3);          // bijective (512 % 8 == 0)
    const int n0 = (lin & 1) * 128;
    const int m0 = (lin >> 1) * 64;

    // staging: A tiles 64x32 (4KB) = 1 round; B tiles 128x32 (8KB) = 2 rounds
    const int arow = tid >> 2, acb = tid & 3;
    const int brow1 = (256 + tid) >> 2, bcb1 = (256 + tid) & 3;

    const unsigned short* aGp  = Hm  + (size_t)(m0 + arow) * 2048 + acb * 8;
    const unsigned short* aGq  = aGp + 1024;
    const unsigned short* bGp0 = W2T + (size_t)(n0 + arow) * 1024 + acb * 8;
    const unsigned short* bGp1 = W2T + (size_t)(n0 + brow1) * 1024 + bcb1 * 8;
    const unsigned short* bGq0 = bGp0 + 256 * 1024;
    const unsigned short* bGq1 = bGp1 + 256 * 1024;

    unsigned short* dAp  = sAp + wave * 512;
    unsigned short* dAq  = sAq + wave * 512;
    unsigned short* dBp0 = sBp + wave * 512;
    unsigned short* dBp1 = sBp + 2048 + wave * 512;
    unsigned short* dBq0 = sBq + wave * 512;
    unsigned short* dBq1 = sBq + 2048 + wave * 512;

    const int wn = wave * 32;   // wave's 32-col slice of the 128-col tile
    const int lr = lane & 15;
    const int kq = (lane >> 4) * 8;

    f32x4 accp[4][2] = {};
    f32x4 accq[4][2] = {};

    for (int k0 = 0; k0 < 1024; k0 += 32) {
        gld_lds16(aGp  + k0, dAp);
        gld_lds16(aGq  + k0, dAq);
        gld_lds16(bGp0 + k0, dBp0);
        gld_lds16(bGp1 + k0, dBp1);
        gld_lds16(bGq0 + k0, dBq0);
        gld_lds16(bGq1 + k0, dBq1);
        __syncthreads();

        short8 afp[4], afq[4], bp[2], bq[2];
        #pragma unroll
        for (int i = 0; i < 4; ++i) {
            afp[i] = *(const short8*)&sAp[(i * 16 + lr) * 32 + kq];
            afq[i] = *(const short8*)&sAq[(i * 16 + lr) * 32 + kq];
        }
        #pragma unroll
        for (int j = 0; j < 2; ++j) {
            bp[j] = *(const short8*)&sBp[(wn + j * 16 + lr) * 32 + kq];
            bq[j] = *(const short8*)&sBq[(wn + j * 16 + lr) * 32 + kq];
        }

        #pragma unroll
        for (int i = 0; i < 4; ++i)
            #pragma unroll
            for (int j = 0; j < 2; ++j) {
                accp[i][j] = __builtin_amdgcn_mfma_f32_16x16x32_bf16(afp[i], bp[j], accp[i][j], 0, 0, 0);
                accq[i][j] = __builtin_amdgcn_mfma_f32_16x16x32_bf16(afq[i], bq[j], accq[i][j], 0, 0, 0);
            }
        __syncthreads();
    }

    // epilogue: per (row, col): write drift/diffusion, accumulate dkl per row
    const int rquad = (lane >> 4) * 4;
    float bcv[2], bhv[2], dv[2], sdv[2], imv[2];
    #pragma unroll
    for (int j = 0; j < 2; ++j) {
        const int gc = n0 + wn + j * 16 + lr;
        bcv[j] = bias2[gc];
        bhv[j] = bias2[256 + gc];
        float d = dfu[gc];
        dv[j] = d;
        float sgn = (d > 0.f) ? 1.f : ((d < 0.f) ? -1.f : 0.f);
        sdv[j] = (fabsf(d) > 1e-7f) ? d : sgn * 1e-7f;
        imv[j] = im[gc];
    }

    #pragma unroll
    for (int i = 0; i < 4; ++i) {
        #pragma unroll
        for (int r = 0; r < 4; ++r) {
            const int gr = m0 + i * 16 + rquad + r;
            float* drift = out + (size_t)gr * 513;
            float* dif   = out + (size_t)NB * 513 + (size_t)gr * 513;
            float s2 = 0.f;
            #pragma unroll
            for (int j = 0; j < 2; ++j) {
                const int gc = n0 + wn + j * 16 + lr;
                float post = accp[i][j][r] + bcv[j];
                float pri  = accq[i][j][r] + bhv[j];
                drift[256 + gc] = post;
                drift[gc]       = imv[j] * z[(size_t)gr * 513 + 256 + gc];
                dif[gc]         = 0.f;
                dif[256 + gc]   = dv[j];
                float qq = (pri - post) / sdv[j];
                s2 += qq * qq;
            }
            // reduce across the 16 lanes of this quad (they hold this row's 32 cols)
            #pragma unroll
            for (int m = 1; m < 16; m <<= 1) s2 += __shfl_xor(s2, m, 64);
            if (lr == 0) atomicAdd(&drift[512], s2);
        }
    }
}

extern "C" void kernel_launch(void* const* d_in, const int* in_sizes, int n_in,
                              void* d_out, int out_size, void* d_ws, size_t ws_size,
                              hipStream_t stream) {
    const float* z    = (const float*)d_in[0];
    const float* ts   = (const float*)d_in[1];
    const float* t    = (const float*)d_in[2];
    const float* ctx  = (const float*)d_in[3];
    const float* im   = (const float*)d_in[4];
    const float* dfu  = (const float*)d_in[5];
    const float* Wc1  = (const float*)d_in[6];
    const float* bc1  = (const float*)d_in[7];
    const float* Wc2  = (const float*)d_in[8];
    const float* bc2  = (const float*)d_in[9];
    const float* Wh1  = (const float*)d_in[10];
    const float* bh1  = (const float*)d_in[11];
    const float* Wh2  = (const float*)d_in[12];
    const float* bh2  = (const float*)d_in[13];

    char* ws = (char*)d_ws;
    unsigned short* A1  = (unsigned short*)(ws);                       // 33,554,432 B
    unsigned short* H   = (unsigned short*)(ws + 33554432ull);         // 67,108,864 B
    unsigned short* W1T = (unsigned short*)(ws + 100663296ull);        //  4,194,304 B
    unsigned short* W2T = (unsigned short*)(ws + 104857600ull);        //  1,048,576 B
    float*          b1  = (float*)(ws + 105906176ull);                 //      8,192 B
    float*          b2  = (float*)(ws + 105914368ull);                 //      2,048 B

    float* out = (float*)d_out;

    build_w<<<10250, 256, 0, stream>>>(Wc1, bc1, Wc2, bc2, Wh1, bh1, Wh2, bh2, W1T, W2T, b1, b2);
    build_A1<<<8192, 256, 0, stream>>>(z, ts, t, ctx, A1, out);

    dim3 g1(16, 128);
    gemm1<<<g1, 256, 0, stream>>>(A1, W1T, b1, H);

    dim3 g2(2, 256);
    gemm2_fused<<<g2, 256, 0, stream>>>(H, W2T, b2, z, im, dfu, out);
}

// Round 2
// 773.088 us; speedup vs baseline: 1.0661x; 1.0420x over previous
//
#include <hip/hip_runtime.h>

typedef __attribute__((ext_vector_type(8))) short short8;
typedef __attribute__((ext_vector_type(4))) float f32x4;

#define AS1 __attribute__((address_space(1)))
#define AS3 __attribute__((address_space(3)))

// sizes
#define NB 16384      // batch
#define LDIM 256
#define CDIM 512
#define HDIM 1024

__device__ __forceinline__ unsigned short f2bf(float x) {
    unsigned u = __float_as_uint(x);
    u += 0x7fffu + ((u >> 16) & 1u);   // RNE; inputs are finite, no NaN guard needed
    return (unsigned short)(u >> 16);
}

__device__ __forceinline__ void gld_lds16(const unsigned short* g, unsigned short* l) {
    __builtin_amdgcn_global_load_lds((const AS1 void*)g, (AS3 void*)l, 16, 0, 0);
}

__device__ __forceinline__ float tanh_fast(float x) {
    x = fminf(fmaxf(x, -15.f), 15.f);
    float e = __expf(2.f * x);
    return (e - 1.f) * __builtin_amdgcn_rcpf(e + 1.f);   // 1-ulp rcp; output is bf16
}

// ---------------- weight conversion via LDS-tiled transpose (coalesced both sides) ----
// W1T (2048 x 1024 bf16): rows 0..1023 = Wc1^T, rows 1024..2047 = Wh1^T (k<512), 0 else
// W2T (512 x 1024 bf16):  rows 0..255  = Wc2^T, rows 256..511  = Wh2^T
// bias1 (2048 f32) = [bc1|bh1]; bias2 (512 f32) = [bc2|bh2]
// blocks 0..511: W1T 64x64 tiles; 512..639: W2T tiles; 640..649: biases
__global__ __launch_bounds__(256)
void build_w(const float* __restrict__ Wc1, const float* __restrict__ bc1,
             const float* __restrict__ Wc2, const float* __restrict__ bc2,
             const float* __restrict__ Wh1, const float* __restrict__ bh1,
             const float* __restrict__ Wh2, const float* __restrict__ bh2,
             unsigned short* __restrict__ W1T, unsigned short* __restrict__ W2T,
             float* __restrict__ bias1, float* __restrict__ bias2)
{
    __shared__ float s[64][65];
    const int bid = blockIdx.x;
    const int tid = threadIdx.x;

    if (bid >= 640) {   // biases
        int id = (bid - 640) * 256 + tid;
        if (id < 2048)      bias1[id] = (id < 1024) ? bc1[id] : bh1[id - 1024];
        else if (id < 2560) { int n = id - 2048; bias2[n] = (n < 256) ? bc2[n] : bh2[n - 256]; }
        return;
    }

    const int tk = bid & 15;           // k-tile (both dst have 1024 k-cols)
    const int k0 = tk * 64;
    const float* src; int srcStride, n0s, kmax, dn0;
    unsigned short* dst;
    if (bid < 512) {                   // W1T, n-tiles 0..31
        const int tn = bid >> 4;
        dst = W1T; dn0 = tn * 64; srcStride = 1024;
        if (tn < 16) { src = Wc1; n0s = tn * 64;        kmax = 1024; }
        else         { src = Wh1; n0s = (tn - 16) * 64; kmax = 512;  }
    } else {                           // W2T, n-tiles 0..7
        const int tn = (bid - 512) >> 4;
        dst = W2T; dn0 = tn * 64; srcStride = 256;
        if (tn < 4) { src = Wc2; n0s = tn * 64;       kmax = 1024; }
        else        { src = Wh2; n0s = (tn - 4) * 64; kmax = 1024; }
    }

    // read: 64(k-rows) x 64(n-cols) f32 tile, coalesced float4
    #pragma unroll
    for (int rd = 0; rd < 4; ++rd) {
        int e = rd * 1024 + tid * 4;
        int r = e >> 6;            // k-row in tile
        int c = e & 63;            // n-col in tile (mult of 4)
        f32x4 v = {0.f, 0.f, 0.f, 0.f};
        int k = k0 + r;
        if (k < kmax) v = *(const f32x4*)(src + (size_t)k * srcStride + n0s + c);
        s[r][c + 0] = v[0]; s[r][c + 1] = v[1]; s[r][c + 2] = v[2]; s[r][c + 3] = v[3];
    }
    __syncthreads();

    // write: 64(n-rows) x 64(k-cols) bf16, coalesced short8
    #pragma unroll
    for (int wr = 0; wr < 2; ++wr) {
        int e = wr * 2048 + tid * 8;
        int on = e >> 6;           // n-row in tile
        int ok = e & 63;           // k-col (mult of 8)
        short8 o;
        #pragma unroll
        for (int j = 0; j < 8; ++j) o[j] = (short)f2bf(s[ok + j][on]);
        *(short8*)(dst + (size_t)(dn0 + on) * 1024 + k0 + ok) = o;
    }
}

// ---------------- A1 = bf16([pm | ctx[:, i]]) + GEMM-independent outputs --------------
// Also writes: drift position block (im*momentum), the whole diffusion half of out,
// and zeroes both dkl slots (atomic targets for gemm2).
__global__ void build_A1(const float* __restrict__ z, const float* __restrict__ ts,
                         const float* __restrict__ t, const float* __restrict__ ctx,
                         const float* __restrict__ im, const float* __restrict__ dfu,
                         unsigned short* __restrict__ A1, float* __restrict__ out)
{
    __shared__ int sh_i;
    if (threadIdx.x == 0) {
        float tv = t[0];
        int c = 0;
        #pragma unroll
        for (int q = 0; q < 16; ++q) c += (ts[q] <= tv) ? 1 : 0;   // searchsorted 'right'
        sh_i = (c < 15) ? c : 15;
    }
    __syncthreads();
    const int i = sh_i;
    size_t id = (size_t)blockIdx.x * 256 + threadIdx.x;   // 2,097,152 threads (grid 8192)
    int b  = (int)(id >> 7);
    int c0 = ((int)id & 127) << 3;
    short8 v;
    if (c0 < 512) {
        const float* zp = z + (size_t)b * 513 + c0;        // row base not 16B-aligned (513)
        float zv[8];
        #pragma unroll
        for (int q = 0; q < 8; ++q) zv[q] = zp[q];
        #pragma unroll
        for (int q = 0; q < 8; ++q) v[q] = (short)f2bf(zv[q]);
        float* drift = out + (size_t)b * 513;
        float* dif   = out + (size_t)NB * 513 + (size_t)b * 513;
        if (c0 < 256) {
            #pragma unroll
            for (int q = 0; q < 8; ++q) dif[c0 + q] = 0.f;           // diffusion position block
        } else {
            int mc = c0 - 256;
            #pragma unroll
            for (int q = 0; q < 8; ++q) {
                drift[mc + q] = im[mc + q] * zv[q];                   // position drift
                dif[c0 + q]   = dfu[mc + q];                          // diffusion momentum block
            }
        }
    } else {
        const f32x4* cp = (const f32x4*)(ctx + ((size_t)b * 16 + i) * 512 + (c0 - 512));
        f32x4 x0 = cp[0], x1 = cp[1];
        #pragma unroll
        for (int q = 0; q < 4; ++q) { v[q] = (short)f2bf(x0[q]); v[4 + q] = (short)f2bf(x1[q]); }
    }
    *(short8*)(A1 + id * 8) = v;
    if (id < NB) {
        out[id * 513 + 512] = 0.f;                          // drift dkl slot (atomic target)
        out[(size_t)NB * 513 + id * 513 + 512] = 0.f;       // diffusion dkl slot
    }
}

// ---------------- layer-1 bf16 MFMA GEMM, m97 structure, XCD-swizzled ----------------
// 128x128 tile, BK=32, 4 waves of 64x64, 16x16x32 MFMA.
// C = tanh(A1 @ W1 + bias1) -> H bf16 (ldc 2048); ntile>=8 (prior half) uses K=512
__global__ __launch_bounds__(256)
void gemm1(const unsigned short* __restrict__ A, const unsigned short* __restrict__ BT,
           const float* __restrict__ bias, unsigned short* __restrict__ Hout)
{
    __shared__ unsigned short sA[128 * 32];
    __shared__ unsigned short sB[128 * 32];

    const int tid  = threadIdx.x;
    const int lane = tid & 63;
    const int wave = tid >> 6;

    // XCD swizzle: 2048 wgs -> 256-wg contiguous chunk per XCD (16 consecutive m-tiles).
    int lin = blockIdx.y * 16 + blockIdx.x;
    lin = (lin & 7) * 256 + (lin >> 3);         // bijective (2048 % 8 == 0)
    const int ntile = lin & 15;
    const int mtile = lin >> 4;
    const int kdim  = (ntile < 8) ? 1024 : 512;

    const int m0 = mtile * 128;
    const int n0 = ntile * 128;

    const int row0 = tid >> 2,         cb0 = tid & 3;
    const int row1 = (256 + tid) >> 2, cb1 = (256 + tid) & 3;

    const unsigned short* aG0 = A + (size_t)(m0 + row0) * 1024 + cb0 * 8;
    const unsigned short* aG1 = A + (size_t)(m0 + row1) * 1024 + cb1 * 8;
    const unsigned short* bG0 = BT + (size_t)(n0 + row0) * 1024 + cb0 * 8;
    const unsigned short* bG1 = BT + (size_t)(n0 + row1) * 1024 + cb1 * 8;

    // wave-uniform LDS bases (HW adds lane*16B)
    unsigned short* sA0 = sA + (size_t)(wave * 64) * 8;
    unsigned short* sA1 = sA + (size_t)(256 + wave * 64) * 8;
    unsigned short* sB0 = sB + (size_t)(wave * 64) * 8;
    unsigned short* sB1 = sB + (size_t)(256 + wave * 64) * 8;

    const int wm = (wave & 1) * 64;
    const int wn = (wave >> 1) * 64;
    const int lr = lane & 15;
    const int kq = (lane >> 4) * 8;

    f32x4 acc[4][4] = {};

    for (int k0 = 0; k0 < kdim; k0 += 32) {
        gld_lds16(aG0 + k0, sA0);
        gld_lds16(aG1 + k0, sA1);
        gld_lds16(bG0 + k0, sB0);
        gld_lds16(bG1 + k0, sB1);
        __syncthreads();

        short8 af[4], bfr[4];
        #pragma unroll
        for (int i = 0; i < 4; ++i)
            af[i] = *(const short8*)&sA[(wm + i * 16 + lr) * 32 + kq];
        #pragma unroll
        for (int i = 0; i < 4; ++i)
            bfr[i] = *(const short8*)&sB[(wn + i * 16 + lr) * 32 + kq];

        #pragma unroll
        for (int i = 0; i < 4; ++i)
            #pragma unroll
            for (int j = 0; j < 4; ++j)
                acc[i][j] = __builtin_amdgcn_mfma_f32_16x16x32_bf16(af[i], bfr[j], acc[i][j], 0, 0, 0);
        __syncthreads();
    }

    // epilogue: C/D layout col=lane&15, row=(lane>>4)*4+reg
    const int rquad = (lane >> 4) * 4;
    #pragma unroll
    for (int i = 0; i < 4; ++i) {
        const int gr = m0 + wm + i * 16 + rquad;
        #pragma unroll
        for (int j = 0; j < 4; ++j) {
            const int gc = n0 + wn + j * 16 + lr;
            const float bs = bias[gc];
            #pragma unroll
            for (int r = 0; r < 4; ++r) {
                float x = acc[i][j][r] + bs;
                Hout[(size_t)(gr + r) * 2048 + gc] = f2bf(tanh_fast(x));
            }
        }
    }
}

// ---------------- layer-2 GEMM fused with posterior write + dkl ----------------------
// 512 threads (8 waves), 64 rows x 128 cols of BOTH halves; each wave owns a 16-col
// slice. 16 waves/CU (vs 8 before) for latency hiding. Epilogue: one coalesced
// posterior store + per-row dkl partial (16-lane shuffle + atomicAdd).
__global__ __launch_bounds__(512)
void gemm2_fused(const unsigned short* __restrict__ Hm, const unsigned short* __restrict__ W2T,
                 const float* __restrict__ bias2, const float* __restrict__ dfu,
                 float* __restrict__ out)
{
    __shared__ unsigned short sAp[64 * 32];    // posterior A tile (H cols k0..k0+31)
    __shared__ unsigned short sAq[64 * 32];    // prior    A tile (H cols 1024+k0..)
    __shared__ unsigned short sBp[128 * 32];   // Wc2^T rows n0..n0+127
    __shared__ unsigned short sBq[128 * 32];   // Wh2^T rows 256+n0..

    const int tid  = threadIdx.x;
    const int lane = tid & 63;
    const int w    = tid >> 6;                 // 0..7

    // XCD swizzle: 512 wgs -> 64 contiguous per XCD (H panel locality)
    int lin = blockIdx.y * 2 + blockIdx.x;
    lin = (lin & 7) * 64 + (lin >> 3);          // bijective (512 % 8 == 0)
    const int n0 = (lin & 1) * 128;
    const int m0 = (lin >> 1) * 64;

    // staging (3 wave-rounds x 1KB each; wave-uniform LDS base + lane*16B):
    //  round A: waves 0-3 -> sAp quarter w;   waves 4-7 -> sAq quarter (w-4)
    //  round B0: wave w -> sBp rows 16w..16w+15;  round B1: wave w -> sBq rows 16w..
    const int srow = lane >> 2;                 // 0..15
    const int cb   = lane & 3;
    const int aseg = w & 3;
    const unsigned short* aG = Hm + (size_t)(m0 + aseg * 16 + srow) * 2048
                                  + ((w >> 2) ? 1024 : 0) + cb * 8;
    unsigned short* aL = ((w >> 2) ? sAq : sAp) + aseg * 512;
    const unsigned short* bpG = W2T + (size_t)(n0 + w * 16 + srow) * 1024 + cb * 8;
    const unsigned short* bqG = bpG + 256 * 1024;
    unsigned short* bpL = sBp + w * 512;
    unsigned short* bqL = sBq + w * 512;

    const int wn = w * 16;                      // wave's 16-col slice
    const int lr = lane & 15;
    const int kq = (lane >> 4) * 8;

    f32x4 accp[4] = {};
    f32x4 accq[4] = {};

    for (int k0 = 0; k0 < 1024; k0 += 32) {
        gld_lds16(aG  + k0, aL);
        gld_lds16(bpG + k0, bpL);
        gld_lds16(bqG + k0, bqL);
        __syncthreads();

        short8 afp[4], afq[4], bp, bq;
        #pragma unroll
        for (int i = 0; i < 4; ++i) {
            afp[i] = *(const short8*)&sAp[(i * 16 + lr) * 32 + kq];
            afq[i] = *(const short8*)&sAq[(i * 16 + lr) * 32 + kq];
        }
        bp = *(const short8*)&sBp[(wn + lr) * 32 + kq];
        bq = *(const short8*)&sBq[(wn + lr) * 32 + kq];

        #pragma unroll
        for (int i = 0; i < 4; ++i) {
            accp[i] = __builtin_amdgcn_mfma_f32_16x16x32_bf16(afp[i], bp, accp[i], 0, 0, 0);
            accq[i] = __builtin_amdgcn_mfma_f32_16x16x32_bf16(afq[i], bq, accq[i], 0, 0, 0);
        }
        __syncthreads();
    }

    // epilogue
    const int gc = n0 + wn + lr;
    const float bcv = bias2[gc];
    const float bhv = bias2[256 + gc];
    float d   = dfu[gc];
    float sgn = (d > 0.f) ? 1.f : ((d < 0.f) ? -1.f : 0.f);
    float sd  = (fabsf(d) > 1e-7f) ? d : sgn * 1e-7f;
    const int rquad = (lane >> 4) * 4;

    #pragma unroll
    for (int i = 0; i < 4; ++i) {
        #pragma unroll
        for (int r = 0; r < 4; ++r) {
            const int gr = m0 + i * 16 + rquad + r;
            float post = accp[i][r] + bcv;
            float pri  = accq[i][r] + bhv;
            out[(size_t)gr * 513 + 256 + gc] = post;
            float qq = (pri - post) / sd;
            float s2 = qq * qq;
            #pragma unroll
            for (int m = 1; m < 16; m <<= 1) s2 += __shfl_xor(s2, m, 64);
            if (lr == 0) atomicAdd(&out[(size_t)gr * 513 + 512], s2);
        }
    }
}

extern "C" void kernel_launch(void* const* d_in, const int* in_sizes, int n_in,
                              void* d_out, int out_size, void* d_ws, size_t ws_size,
                              hipStream_t stream) {
    const float* z    = (const float*)d_in[0];
    const float* ts   = (const float*)d_in[1];
    const float* t    = (const float*)d_in[2];
    const float* ctx  = (const float*)d_in[3];
    const float* im   = (const float*)d_in[4];
    const float* dfu  = (const float*)d_in[5];
    const float* Wc1  = (const float*)d_in[6];
    const float* bc1  = (const float*)d_in[7];
    const float* Wc2  = (const float*)d_in[8];
    const float* bc2  = (const float*)d_in[9];
    const float* Wh1  = (const float*)d_in[10];
    const float* bh1  = (const float*)d_in[11];
    const float* Wh2  = (const float*)d_in[12];
    const float* bh2  = (const float*)d_in[13];

    char* ws = (char*)d_ws;
    unsigned short* A1  = (unsigned short*)(ws);                       // 33,554,432 B
    unsigned short* H   = (unsigned short*)(ws + 33554432ull);         // 67,108,864 B
    unsigned short* W1T = (unsigned short*)(ws + 100663296ull);        //  4,194,304 B
    unsigned short* W2T = (unsigned short*)(ws + 104857600ull);        //  1,048,576 B
    float*          b1  = (float*)(ws + 105906176ull);                 //      8,192 B
    float*          b2  = (float*)(ws + 105914368ull);                 //      2,048 B

    float* out = (float*)d_out;

    build_w<<<650, 256, 0, stream>>>(Wc1, bc1, Wc2, bc2, Wh1, bh1, Wh2, bh2, W1T, W2T, b1, b2);
    build_A1<<<8192, 256, 0, stream>>>(z, ts, t, ctx, im, dfu, A1, out);

    dim3 g1(16, 128);
    gemm1<<<g1, 256, 0, stream>>>(A1, W1T, b1, H);

    dim3 g2(2, 256);
    gemm2_fused<<<g2, 512, 0, stream>>>(H, W2T, b2, dfu, out);
}